// Round 4
// baseline (34435.110 us; speedup 1.0000x reference)
//
#include <hip/hip_runtime.h>
#include <hip/hip_bf16.h>

#define S_LEN 512
#define BATCH 64
#define H_DIM 1024
#define NLAYER 2
#define G3 3072           // 3*H
#define CS 128            // timestep chunk
#define CROWS (CS*BATCH)  // 8192 rows per proj chunk
#define BH 65536          // BATCH*H_DIM

typedef __bf16 bf16_t;
typedef __bf16 bf16x8_t __attribute__((ext_vector_type(8)));
typedef __bf16 bf16x4_t __attribute__((ext_vector_type(4)));
typedef float f32x4 __attribute__((ext_vector_type(4)));
typedef unsigned int uint32;

__device__ __forceinline__ float sigmoidf_(float x) { return 1.0f / (1.0f + __expf(-x)); }

__device__ __forceinline__ void split2(float f, bf16_t& hi, bf16_t& lo) {
    hi = (bf16_t)f;
    lo = (bf16_t)(f - (float)hi);
}

// ---------------- split f32 -> (bf16 hi, bf16 lo) ----------------
__global__ void split_kernel(const float* __restrict__ in, bf16_t* __restrict__ hi,
                             bf16_t* __restrict__ lo, int n4) {
    int i = blockIdx.x * blockDim.x + threadIdx.x;
    int stride = gridDim.x * blockDim.x;
    for (; i < n4; i += stride) {
        f32x4 v = *(const f32x4*)(in + 4 * (size_t)i);
        bf16x4_t h, l;
#pragma unroll
        for (int j = 0; j < 4; ++j) { bf16_t a, b; split2(v[j], a, b); h[j] = a; l[j] = b; }
        *(bf16x4_t*)(hi + 4 * (size_t)i) = h;
        *(bf16x4_t*)(lo + 4 * (size_t)i) = l;
    }
}

// ---------------- projection GEMM (unchanged from round 2, passed) ----------------
__global__ __launch_bounds__(256) void proj_kernel(
    const bf16_t* __restrict__ Ah, const bf16_t* __restrict__ Al,
    const bf16_t* __restrict__ Wh, const bf16_t* __restrict__ Wl,
    const float* __restrict__ bias,
    float* __restrict__ Cout)
{
    __shared__ bf16_t sA[2][128][72];
    __shared__ bf16_t sW[2][128][72];
    const int tid = threadIdx.x;
    const int lane = tid & 63;
    const int w = tid >> 6;
    const int wm = w >> 1, wn = w & 1;
    const int bn = blockIdx.x, bm = blockIdx.y;
    const int fr = lane & 15;
    const int fq = lane >> 4;

    f32x4 acc[4][4] = {};

    const bf16_t* A0 = Ah + (size_t)bm * 128 * 1024;
    const bf16_t* A1 = Al + (size_t)bm * 128 * 1024;
    const bf16_t* W0 = Wh + (size_t)bn * 128 * 1024;
    const bf16_t* W1 = Wl + (size_t)bn * 128 * 1024;

    for (int kt = 0; kt < 16; ++kt) {
        const int k0 = kt * 64;
#pragma unroll
        for (int it = 0; it < 4; ++it) {
            int g = tid + it * 256;
            int row = g >> 3, c8 = (g & 7) * 8;
            size_t so = (size_t)row * 1024 + k0 + c8;
            *(bf16x8_t*)&sA[0][row][c8] = *(const bf16x8_t*)(A0 + so);
            *(bf16x8_t*)&sA[1][row][c8] = *(const bf16x8_t*)(A1 + so);
            *(bf16x8_t*)&sW[0][row][c8] = *(const bf16x8_t*)(W0 + so);
            *(bf16x8_t*)&sW[1][row][c8] = *(const bf16x8_t*)(W1 + so);
        }
        __syncthreads();
#pragma unroll
        for (int kk = 0; kk < 2; ++kk) {
            const int koff = kk * 32 + fq * 8;
            bf16x8_t ah[4], al[4], wh8[4], wl8[4];
#pragma unroll
            for (int mt = 0; mt < 4; ++mt) {
                ah[mt] = *(const bf16x8_t*)&sA[0][wm * 64 + mt * 16 + fr][koff];
                al[mt] = *(const bf16x8_t*)&sA[1][wm * 64 + mt * 16 + fr][koff];
            }
#pragma unroll
            for (int nt = 0; nt < 4; ++nt) {
                wh8[nt] = *(const bf16x8_t*)&sW[0][wn * 64 + nt * 16 + fr][koff];
                wl8[nt] = *(const bf16x8_t*)&sW[1][wn * 64 + nt * 16 + fr][koff];
            }
#pragma unroll
            for (int mt = 0; mt < 4; ++mt)
#pragma unroll
                for (int nt = 0; nt < 4; ++nt) {
                    acc[mt][nt] = __builtin_amdgcn_mfma_f32_16x16x32_bf16(ah[mt], wh8[nt], acc[mt][nt], 0, 0, 0);
                    acc[mt][nt] = __builtin_amdgcn_mfma_f32_16x16x32_bf16(ah[mt], wl8[nt], acc[mt][nt], 0, 0, 0);
                    acc[mt][nt] = __builtin_amdgcn_mfma_f32_16x16x32_bf16(al[mt], wh8[nt], acc[mt][nt], 0, 0, 0);
                }
        }
        __syncthreads();
    }
#pragma unroll
    for (int nt = 0; nt < 4; ++nt) {
        int n = bn * 128 + wn * 64 + nt * 16 + fr;
        float bv = bias[n];
#pragma unroll
        for (int mt = 0; mt < 4; ++mt) {
#pragma unroll
            for (int r = 0; r < 4; ++r) {
                int m = bm * 128 + wm * 64 + mt * 16 + fq * 4 + r;
                Cout[(size_t)m * G3 + n] = acc[mt][nt][r] + bv;
            }
        }
    }
}

// ---------------- persistent recurrence: 128 steps per launch ----------------
// grid 256 blocks x 512 threads, 1 block/CU (128 KB LDS). Block owns
// (batch-half of 32) x (8 j's). W slice (24 rows x 1024, hi+lo) lives in LDS
// for the whole chunk, XOR-swizzled (bits 4-6 ^= row&7 -> 2-way conflict = free).
// h state is stored as bf16 hi/lo in global; custom per-half device-scope
// barrier separates steps. 8 waves split K (128 each), LDS partial reduce.
__global__ __launch_bounds__(512) void rec_chunk_kernel(
    const float* __restrict__ gi,       // [CS][64][3072] chunk
    const bf16_t* __restrict__ Whh, const bf16_t* __restrict__ Whl,
    const float* __restrict__ bhl,      // [3072]
    const bf16_t* __restrict__ h0_hi, const bf16_t* __restrict__ h0_lo,  // layer h0 split
    bf16_t* __restrict__ sxh, bf16_t* __restrict__ sxl,   // layer0: seq hi/lo (full arrays)
    bf16_t* __restrict__ hbh0, bf16_t* __restrict__ hbl0, // layer1 state parity 0
    bf16_t* __restrict__ hbh1, bf16_t* __restrict__ hbl1, // layer1 state parity 1
    float* __restrict__ out_seq,        // layer1: d_out seq base, else null
    float* __restrict__ hn_out,         // d_out h_n slot for this layer
    uint32* __restrict__ bar, int t0, int layer)
{
    __shared__ bf16_t sWh[24][1024];
    __shared__ bf16_t sWl[24][1024];
    __shared__ float sP[8][32][32];

    const int tid = threadIdx.x;
    const int lane = tid & 63;
    const int w = tid >> 6;          // 0..7
    const int bid = blockIdx.x;
    const int half = bid & 1;
    const int b0 = half * 32;
    const int j0 = (bid >> 1) * 8;
    const int fr = lane & 15, fq = lane >> 4;

    uint32* cnt  = bar + half * 32;        // 128B apart
    uint32* flag = bar + half * 32 + 16;   // own cache line

    char* w0 = (char*)&sWh[0][0];
    char* w1 = (char*)&sWl[0][0];

    // ---- load W slice into LDS once (swizzled) ----
#pragma unroll
    for (int it = 0; it < 6; ++it) {
        int g = tid + it * 512;            // 0..3071
        int row = g >> 7;                  // 0..23  (gate = row>>3, jj = row&7)
        int c8 = (g & 127) * 8;
        size_t so = (size_t)((row >> 3) * 1024 + j0 + (row & 7)) * 1024 + c8;
        uint32 off = (uint32)(row * 2048 + c8 * 2) ^ (uint32)((row & 7) << 4);
        *(bf16x8_t*)(w0 + off) = *(const bf16x8_t*)(Whh + so);
        *(bf16x8_t*)(w1 + off) = *(const bf16x8_t*)(Whl + so);
    }
    __syncthreads();

    // per-wave constants
    const int k0 = w * 128;
    int wr0 = fr;                                   // nt=0 rows 0..15
    int wr1 = (16 + fr < 24) ? (16 + fr) : 23;      // nt=1 rows 16..23 (clamped; cols 24..31 unused)
    const uint32 wb0 = (uint32)(wr0 * 2048), wx0 = (uint32)((wr0 & 7) << 4);
    const uint32 wb1 = (uint32)(wr1 * 2048), wx1 = (uint32)((wr1 & 7) << 4);

    // pointwise thread mapping + hoisted bias
    const int pb = tid >> 3, pj = tid & 7;          // valid when tid<256
    const int pbg = b0 + pb, pjg = j0 + pj;
    float br = 0.f, bz = 0.f, bn_ = 0.f;
    if (tid < 256) { br = bhl[pjg]; bz = bhl[1024 + pjg]; bn_ = bhl[2048 + pjg]; }

    for (int tt = 0; tt < CS; ++tt) {
        const int t = t0 + tt;

        // gi loads are barrier-independent: issue before the wait to hide latency
        float gr = 0.f, gz = 0.f, gn = 0.f;
        if (tid < 256) {
            const float* gib = gi + ((size_t)tt * 64 + pbg) * G3;
            gr = gib[pjg]; gz = gib[1024 + pjg]; gn = gib[2048 + pjg];
        }

        // ---- wait for previous step (epoch tt) ----
        if (tt > 0) {
            if (tid == 0) {
                while (__hip_atomic_load(flag, __ATOMIC_ACQUIRE, __HIP_MEMORY_SCOPE_AGENT) < (uint32)tt)
                    __builtin_amdgcn_s_sleep(1);
                __threadfence();   // acquire: invalidate L1/L2 so remote h is visible
            }
            __syncthreads();
        }

        // ---- per-step state pointers ----
        const bf16_t *hH, *hL;
        bf16_t *sH_, *sL_;
        if (layer == 0) {
            hH = (t == 0) ? h0_hi : sxh + (size_t)(t - 1) * BH;
            hL = (t == 0) ? h0_lo : sxl + (size_t)(t - 1) * BH;
            sH_ = sxh + (size_t)t * BH;
            sL_ = sxl + (size_t)t * BH;
        } else {
            hH = (t == 0) ? h0_hi : ((t & 1) ? hbh0 : hbh1);
            hL = (t == 0) ? h0_lo : ((t & 1) ? hbl0 : hbl1);
            sH_ = (t & 1) ? hbh1 : hbh0;
            sL_ = (t & 1) ? hbl1 : hbl0;
        }

        // ---- A fragments: direct global->reg, all issued up front ----
        bf16x8_t ah[4][2], al[4][2];
#pragma unroll
        for (int kk = 0; kk < 4; ++kk) {
            const int kg = k0 + kk * 32 + fq * 8;
#pragma unroll
            for (int mt = 0; mt < 2; ++mt) {
                size_t ro = (size_t)(b0 + mt * 16 + fr) * 1024 + kg;
                ah[kk][mt] = *(const bf16x8_t*)(hH + ro);
                al[kk][mt] = *(const bf16x8_t*)(hL + ro);
            }
        }

        f32x4 acc[2][2] = {};
#pragma unroll
        for (int kk = 0; kk < 4; ++kk) {
            const uint32 kb = (uint32)((k0 + kk * 32 + fq * 8) * 2);
            bf16x8_t wh8[2], wl8[2];
            wh8[0] = *(const bf16x8_t*)(w0 + ((wb0 + kb) ^ wx0));
            wl8[0] = *(const bf16x8_t*)(w1 + ((wb0 + kb) ^ wx0));
            wh8[1] = *(const bf16x8_t*)(w0 + ((wb1 + kb) ^ wx1));
            wl8[1] = *(const bf16x8_t*)(w1 + ((wb1 + kb) ^ wx1));
#pragma unroll
            for (int mt = 0; mt < 2; ++mt)
#pragma unroll
                for (int nt = 0; nt < 2; ++nt) {
                    bf16x8_t wh_ = nt ? wh8[1] : wh8[0];
                    bf16x8_t wl_ = nt ? wl8[1] : wl8[0];
                    acc[mt][nt] = __builtin_amdgcn_mfma_f32_16x16x32_bf16(ah[kk][mt], wh_, acc[mt][nt], 0, 0, 0);
                    acc[mt][nt] = __builtin_amdgcn_mfma_f32_16x16x32_bf16(ah[kk][mt], wl_, acc[mt][nt], 0, 0, 0);
                    acc[mt][nt] = __builtin_amdgcn_mfma_f32_16x16x32_bf16(al[kk][mt], wh_, acc[mt][nt], 0, 0, 0);
                }
        }

        // ---- split-K partials to LDS ----
#pragma unroll
        for (int mt = 0; mt < 2; ++mt)
#pragma unroll
            for (int nt = 0; nt < 2; ++nt)
#pragma unroll
                for (int r = 0; r < 4; ++r)
                    sP[w][mt * 16 + fq * 4 + r][nt * 16 + fr] = acc[mt][nt][r];
        __syncthreads();

        // ---- pointwise gates ----
        if (tid < 256) {
            float s0 = 0.f, s1 = 0.f, s2 = 0.f;
#pragma unroll
            for (int ww = 0; ww < 8; ++ww) {
                s0 += sP[ww][pb][pj];
                s1 += sP[ww][pb][8 + pj];
                s2 += sP[ww][pb][16 + pj];
            }
            float r = sigmoidf_(gr + s0 + br);
            float z = sigmoidf_(gz + s1 + bz);
            float n = tanhf(gn + r * (s2 + bn_));
            float hprev = (float)hH[(size_t)pbg * 1024 + pjg] + (float)hL[(size_t)pbg * 1024 + pjg];
            float hnew = (1.0f - z) * n + z * hprev;
            bf16_t a, b2; split2(hnew, a, b2);
            sH_[(size_t)pbg * 1024 + pjg] = a;
            sL_[(size_t)pbg * 1024 + pjg] = b2;
            if (out_seq) out_seq[(size_t)t * BH + (size_t)pbg * 1024 + pjg] = hnew;
            if (t == S_LEN - 1) hn_out[(size_t)pbg * 1024 + pjg] = hnew;
        }

        // ---- arrive (release) ----
        if (tt < CS - 1) {
            __syncthreads();  // drains all waves' global stores (vmcnt) before fence
            if (tid == 0) {
                __threadfence();  // release: push stores to coherence point
                uint32 prev = __hip_atomic_fetch_add(cnt, 1u, __ATOMIC_ACQ_REL, __HIP_MEMORY_SCOPE_AGENT);
                if (prev == (uint32)(tt * 128 + 127))
                    __hip_atomic_store(flag, (uint32)(tt + 1), __ATOMIC_RELEASE, __HIP_MEMORY_SCOPE_AGENT);
            }
        }
    }
}

extern "C" void kernel_launch(void* const* d_in, const int* in_sizes, int n_in,
                              void* d_out, int out_size, void* d_ws, size_t ws_size,
                              hipStream_t stream)
{
    (void)in_sizes; (void)n_in; (void)out_size;
    const float* x   = (const float*)d_in[0];
    const float* h0  = (const float*)d_in[1];
    const float* Wi  = (const float*)d_in[2];
    const float* Whw = (const float*)d_in[3];
    const float* bi  = (const float*)d_in[4];
    const float* bh  = (const float*)d_in[5];
    float* out = (float*)d_out;

    char* ws = (char*)d_ws;
    size_t off = 0;
    float*  gi    = (float*)(ws + off);  off += (size_t)CROWS * G3 * 4;           // 96 MB
    bf16_t* sx_hi = (bf16_t*)(ws + off); off += (size_t)S_LEN * BATCH * 1024 * 2; // 64 MB
    bf16_t* sx_lo = (bf16_t*)(ws + off); off += (size_t)S_LEN * BATCH * 1024 * 2; // 64 MB
    bf16_t* wi_hi = (bf16_t*)(ws + off); off += (size_t)NLAYER * G3 * 1024 * 2;   // 12 MB
    bf16_t* wi_lo = (bf16_t*)(ws + off); off += (size_t)NLAYER * G3 * 1024 * 2;
    bf16_t* wh_hi = (bf16_t*)(ws + off); off += (size_t)NLAYER * G3 * 1024 * 2;
    bf16_t* wh_lo = (bf16_t*)(ws + off); off += (size_t)NLAYER * G3 * 1024 * 2;
    bf16_t* h0s_hi = (bf16_t*)(ws + off); off += (size_t)NLAYER * BH * 2;         // 256 KB
    bf16_t* h0s_lo = (bf16_t*)(ws + off); off += (size_t)NLAYER * BH * 2;
    bf16_t* hbh0  = (bf16_t*)(ws + off); off += (size_t)BH * 2;
    bf16_t* hbl0  = (bf16_t*)(ws + off); off += (size_t)BH * 2;
    bf16_t* hbh1  = (bf16_t*)(ws + off); off += (size_t)BH * 2;
    bf16_t* hbl1  = (bf16_t*)(ws + off); off += (size_t)BH * 2;
    off = (off + 255) & ~(size_t)255;
    uint32* bar   = (uint32*)(ws + off); off += 1024;
    if (off > ws_size) return;

    // one-time splits
    split_kernel<<<2048, 256, 0, stream>>>(x, sx_hi, sx_lo, (int)((size_t)S_LEN * BATCH * 1024 / 4));
    split_kernel<<<2048, 256, 0, stream>>>(Wi, wi_hi, wi_lo, (int)((size_t)NLAYER * G3 * 1024 / 4));
    split_kernel<<<2048, 256, 0, stream>>>(Whw, wh_hi, wh_lo, (int)((size_t)NLAYER * G3 * 1024 / 4));
    split_kernel<<<128, 256, 0, stream>>>(h0, h0s_hi, h0s_lo, (int)((size_t)NLAYER * BH / 4));

    for (int l = 0; l < NLAYER; ++l) {
        const bf16_t* WiH = wi_hi + (size_t)l * G3 * 1024;
        const bf16_t* WiL = wi_lo + (size_t)l * G3 * 1024;
        const bf16_t* WhH = wh_hi + (size_t)l * G3 * 1024;
        const bf16_t* WhL = wh_lo + (size_t)l * G3 * 1024;
        const float* bil = bi + (size_t)l * G3;
        const float* bhl = bh + (size_t)l * G3;
        const bf16_t* h0H = h0s_hi + (size_t)l * BH;
        const bf16_t* h0L = h0s_lo + (size_t)l * BH;
        float* hn_slot = out + (size_t)S_LEN * BH + (size_t)l * BH;

        for (int c = 0; c < S_LEN / CS; ++c) {
            proj_kernel<<<dim3(24, 64), 256, 0, stream>>>(
                sx_hi + (size_t)c * CROWS * 1024, sx_lo + (size_t)c * CROWS * 1024,
                WiH, WiL, bil, gi);
            hipMemsetAsync(bar, 0, 1024, stream);
            rec_chunk_kernel<<<256, 512, 0, stream>>>(
                gi, WhH, WhL, bhl, h0H, h0L,
                sx_hi, sx_lo, hbh0, hbl0, hbh1, hbl1,
                (l == 1) ? out : nullptr, hn_slot,
                bar, c * CS, l);
        }
    }
}